// Round 9
// baseline (397.259 us; speedup 1.0000x reference)
//
#include <hip/hip_runtime.h>
#include <stdint.h>

#define B_    1024
#define P_    100
#define N_    101
#define EMB_  128
#define H_    8
#define DK_   16
#define GRID_ 256                  // 1 block/CU; each block loops NPER_ samples
#define NPER_ (B_ / GRID_)         // 4

#define ROWS  112          // 7 m-tiles of 16 (covers P=100 / N=101)
#define KSTR  136          // LDS row stride in bf16 elems

typedef uint16_t bf16;
typedef __attribute__((ext_vector_type(8))) short short8;
typedef __attribute__((ext_vector_type(4))) float float4v;

struct F4 { float x, y, z, w; };   // 4-byte-aligned float quad (101-stride safe)

#define L2E 1.4426950408889634f

#if __has_builtin(__builtin_amdgcn_exp2f)
#define EXP2(x) __builtin_amdgcn_exp2f(x)
#else
#define EXP2(x) exp2f(x)
#endif
#if __has_builtin(__builtin_amdgcn_rcpf)
#define RCP(x) __builtin_amdgcn_rcpf(x)
#else
#define RCP(x) (1.0f / (x))
#endif

__device__ __forceinline__ float b2f(bf16 u) {
    union { uint32_t i; float f; } c; c.i = ((uint32_t)u) << 16; return c.f;
}
// round-half-up f32->bf16 (bias then take high 16): 2 ops
__device__ __forceinline__ bf16 f2b(float f) {
    union { float f; uint32_t i; } c; c.f = f;
    return (bf16)((c.i + 0x8000u) >> 16);
}
// packed pair via v_perm byte-select: 3 ops for 2 values
__device__ __forceinline__ uint32_t pk2(float a, float b) {
    union { float f; uint32_t i; } ca, cb; ca.f = a; cb.f = b;
    return __builtin_amdgcn_perm(cb.i + 0x8000u, ca.i + 0x8000u, 0x07060302u);
}

// ---- cross-sample staging: load f32 rows to regs (issue-early) ------------
__device__ __forceinline__ void stage_load(const float* __restrict__ encB,
                                           const float* __restrict__ elnB,
                                           const float* __restrict__ load_,
                                           const float* __restrict__ time_,
                                           const float* __restrict__ len_,
                                           const float* __restrict__ open_,
                                           int b, int tid,
                                           float4 (&e)[4], float4 (&c)[4],
                                           float& s4v)
{
    #pragma unroll
    for (int j = 0; j < 4; ++j) {
        int i = tid + j * 1024;
        float4 z = {0.f, 0.f, 0.f, 0.f};
        e[j] = z; c[j] = z;
        if (i < ROWS * 32) {
            int r = i >> 5, cc = (i & 31) << 2;
            if (r < N_) e[j] = *(const float4*)(encB + (size_t)r * EMB_ + cc);
            if (r < P_) c[j] = *(const float4*)(elnB + (size_t)r * EMB_ + cc);
        }
    }
    s4v = 0.f;
    if (tid < ROWS * 4) {
        int r = tid >> 2, jj = tid & 3;
        if (r < P_) {
            const float* s4 = (jj == 0) ? load_ : (jj == 1) ? time_
                             : (jj == 2) ? len_ : open_;
            s4v = s4[(size_t)b * P_ + r];
        }
    }
}

// regs -> bf16 LDS [ROWS][KSTR] (write-late, at loop top)
__device__ __forceinline__ void stage_write(const float4 (&v)[4],
                                            bf16* __restrict__ dst, int tid)
{
    #pragma unroll
    for (int j = 0; j < 4; ++j) {
        int i = tid + j * 1024;
        if (i < ROWS * 32) {
            int r = i >> 5, cc = (i & 31) << 2;
            uint32_t* d = (uint32_t*)(dst + r * KSTR + cc);
            d[0] = pk2(v[j].x, v[j].y);
            d[1] = pk2(v[j].z, v[j].w);
        }
    }
}

// ---- prep: W f32 [k][o] -> ws bf16 W^T [o][k], order: Wk, Wv, Wq, Wc ------
__global__ __launch_bounds__(256)
void prep_wT(const float* __restrict__ Wq, const float* __restrict__ Wk,
             const float* __restrict__ Wv, const float* __restrict__ Wc,
             bf16* __restrict__ ws) {
    int idx = blockIdx.x * 256 + threadIdx.x;      // 65536 threads
    int w = idx >> 14, rem = idx & 16383;
    int k = rem >> 7, o = rem & 127;               // o innermost: coalesced read
    const float* W = (w == 0) ? Wk : (w == 1) ? Wv : (w == 2) ? Wq : Wc;
    ws[((size_t)w << 14) + o * 128 + k] = f2b(W[(size_t)k * 128 + o]);
}

__global__ __launch_bounds__(1024, 4)
void vrp_kernel(const float* __restrict__ eln,
                const float* __restrict__ load_,
                const float* __restrict__ time_,
                const float* __restrict__ len_,
                const float* __restrict__ open_,
                const float* __restrict__ mask_,
                const float* __restrict__ enc_,
                const float* __restrict__ Wq,
                const float* __restrict__ bc,
                const bf16* __restrict__ wsWT,
                float* __restrict__ out)
{
    const int tid  = threadIdx.x;
    const int wave = tid >> 6;
    const int lane = tid & 63;
    const int lr = lane & 15, lq = lane >> 4, lk = lq << 3;

    // Overlays: R1 enc (live to F) ; R2 K/mh-lo ; R3 V^T ;
    //           R4 Q/P(hg=1)/O ; R5 cat/P(hg=0)/mh-hi
    __shared__ bf16 smem[78336];
    __shared__ float sS4[ROWS * 4];
    __shared__ float sWq4[4 * EMB_];
    bf16* const R1 = smem;
    bf16* const R2 = smem + 15232;
    bf16* const R3 = smem + 30464;
    bf16* const R4 = smem + 47872;
    bf16* const R5 = smem + 63104;

    const bf16* WkT = wsWT;
    const bf16* WvT = wsWT + 16384;
    const bf16* WqT = wsWT + 32768;
    const bf16* WcT = wsWT + 49152;

    // ---- once-per-block init (persists across the sample loop) ------------
    if (tid < 512) {   // zero sVt[d][112..127]; V^T writes never touch pad
        int d = tid >> 2, c = 112 + ((tid & 3) << 2);
        uint32_t* z = (uint32_t*)(R3 + d * KSTR + c);
        z[0] = 0; z[1] = 0;
    }
    if (tid < 512) {
        int j = tid >> 7, c = tid & 127;
        sWq4[j * EMB_ + c] = Wq[(size_t)(EMB_ + j) * EMB_ + c];
    }

    // prefetch sample 0 of this block into registers
    float4 ereg[4], creg[4];
    float s4v;
    {
        const int b0 = blockIdx.x * NPER_;
        stage_load(enc_ + (size_t)b0 * N_ * EMB_, eln + (size_t)b0 * P_ * EMB_,
                   load_, time_, len_, open_, b0, tid, ereg, creg, s4v);
    }

    for (int s = 0; s < NPER_; ++s) {
        const int b = blockIdx.x * NPER_ + s;
        const float* maskB = mask_ + (size_t)b * P_ * N_;
        float*       outB  = out   + (size_t)b * P_ * N_;

        // ---------------- Phase A: regs -> LDS ----------------------------
        stage_write(ereg, R1, tid);
        stage_write(creg, R5, tid);
        if (tid < ROWS * 4) sS4[tid] = s4v;
        __syncthreads();                            // (1) staging visible

        // mask gather (current sample) issued NOW so HBM latency hides
        // under all of B/C; consumed in D, reused in F.
        const int hg = (wave >= 7) ? 1 : 0;
        const int pt = wave - hg * 7;
        float msk2[7][4];
        if (wave < 14) {
            const int p = pt * 16 + lr;
            const bool pvalid = (p < P_);
            const float* mrow = maskB + (size_t)(pvalid ? p : 0) * N_;
            #pragma unroll
            for (int nt = 0; nt < 6; ++nt) {        // n <= 95 < 101: packed
                int nb = nt * 16 + (lq << 2);
                F4 mv = *(const F4*)(mrow + nb);
                msk2[nt][0] = pvalid ? mv.x * L2E : 0.f;
                msk2[nt][1] = pvalid ? mv.y * L2E : 0.f;
                msk2[nt][2] = pvalid ? mv.z * L2E : 0.f;
                msk2[nt][3] = pvalid ? mv.w * L2E : 0.f;
            }
            if (lq == 0) {                          // nt=6 tail: n=96+4lq+r
                F4 mv = *(const F4*)(mrow + 96);
                msk2[6][0] = pvalid ? mv.x * L2E : 0.f;
                msk2[6][1] = pvalid ? mv.y * L2E : 0.f;
                msk2[6][2] = pvalid ? mv.z * L2E : 0.f;
                msk2[6][3] = pvalid ? mv.w * L2E : 0.f;
            } else if (lq == 1) {
                msk2[6][0] = pvalid ? mrow[100] * L2E : 0.f;
                msk2[6][1] = -3.0e38f; msk2[6][2] = -3.0e38f; msk2[6][3] = -3.0e38f;
            } else {
                msk2[6][0] = -3.0e38f; msk2[6][1] = -3.0e38f;
                msk2[6][2] = -3.0e38f; msk2[6][3] = -3.0e38f;
            }
        }

        // ------- Phase B+C: K->R2, V^T->R3, Q'->R4 ------------------------
        {
            const int col = 16 * (wave & 7) + lr;
            const int mt0 = (wave >> 3) ? 4 : 0;
            const int mt1 = (wave >> 3) ? 7 : 4;
            short8 bk[4], bv[4], bq[4];
            {
                const bf16* rk = WkT + (size_t)col * 128 + lk;
                const bf16* rv = WvT + (size_t)col * 128 + lk;
                const bf16* rq = WqT + (size_t)col * 128 + lk;
                #pragma unroll
                for (int ss = 0; ss < 4; ++ss) {
                    bk[ss] = *(const short8*)(rk + ss * 32);
                    bv[ss] = *(const short8*)(rv + ss * 32);
                    bq[ss] = *(const short8*)(rq + ss * 32);
                }
            }
            float w0 = sWq4[col], w1 = sWq4[EMB_ + col];
            float w2 = sWq4[2 * EMB_ + col], w3 = sWq4[3 * EMB_ + col];
            for (int mt = mt0; mt < mt1; ++mt) {
                short8 a[4];
                #pragma unroll
                for (int ss = 0; ss < 4; ++ss)
                    a[ss] = *(const short8*)(R1 + (mt * 16 + lr) * KSTR + ss * 32 + lk);
                float4v ck = {0.f, 0.f, 0.f, 0.f}, cv = {0.f, 0.f, 0.f, 0.f};
                #pragma unroll
                for (int ss = 0; ss < 4; ++ss) {
                    ck = __builtin_amdgcn_mfma_f32_16x16x32_bf16(a[ss], bk[ss], ck, 0, 0, 0);
                    cv = __builtin_amdgcn_mfma_f32_16x16x32_bf16(a[ss], bv[ss], cv, 0, 0, 0);
                }
                int n0 = mt * 16 + (lq << 2);
                #pragma unroll
                for (int r = 0; r < 4; ++r)
                    R2[(n0 + r) * KSTR + col] = f2b(ck[r]);       // K [n][col]
                uint32_t* d = (uint32_t*)(R3 + col * KSTR + n0);  // V^T [d][n]
                d[0] = pk2(cv[0], cv[1]);
                d[1] = pk2(cv[2], cv[3]);
                // Q' = 0.25*log2e*(cat@Wq)  (log2e baked for exp2)
                short8 aq[4];
                #pragma unroll
                for (int ss = 0; ss < 4; ++ss)
                    aq[ss] = *(const short8*)(R5 + (mt * 16 + lr) * KSTR + ss * 32 + lk);
                float4v cq = {0.f, 0.f, 0.f, 0.f};
                #pragma unroll
                for (int ss = 0; ss < 4; ++ss)
                    cq = __builtin_amdgcn_mfma_f32_16x16x32_bf16(aq[ss], bq[ss], cq, 0, 0, 0);
                int row0 = mt * 16 + (lq << 2);
                #pragma unroll
                for (int r = 0; r < 4; ++r) {
                    const float* s4 = sS4 + (row0 + r) * 4;
                    float acc = cq[r] + s4[0] * w0 + s4[1] * w1 + s4[2] * w2 + s4[3] * w3;
                    R4[(row0 + r) * KSTR + col] = f2b(acc * (0.25f * L2E));
                }
            }
        }
        __syncthreads();                            // (2) K/V/Q ready

        // hoisted Q fragments: heads (0,1) share k-window hg*64, (2,3) +32
        short8 q0, q1;
        if (wave < 14) {
            q0 = *(const short8*)(R4 + (pt * 16 + lr) * KSTR + hg * 64 + lk);
            q1 = *(const short8*)(R4 + (pt * 16 + lr) * KSTR + hg * 64 + 32 + lk);
        }
        __syncthreads();                            // (3) Q consumed -> P bufs

        // >>> prefetch NEXT sample into registers; HBM latency hides under
        //     D+E+F. Regs written to LDS at next loop top (write-late).
        if (s + 1 < NPER_) {
            const int bn = b + 1;
            stage_load(enc_ + (size_t)bn * N_ * EMB_, eln + (size_t)bn * P_ * EMB_,
                       load_, time_, len_, open_, bn, tid, ereg, creg, s4v);
        }

        // -------- Phase D: attention; swapped QK^T, P->LDS roundtrip PV ----
        float4v o4[4];
        if (wave < 14) {
            bf16* Pbuf = hg ? R4 : R5;
            {   // zero pad cols 112..127 of my p-tile rows
                uint32_t* z = (uint32_t*)(Pbuf + (pt * 16 + lr) * KSTR + 112 + (lq << 2));
                z[0] = 0; z[1] = 0;
            }
            #pragma unroll
            for (int hh = 0; hh < 4; ++hh) {
                int h  = hg * 4 + hh;
                int k0 = hg * 64 + (hh >> 1) * 32;  // head's 32-wide k-window
                short8 bq = (hh < 2) ? q0 : q1;
                if ((lq >> 1) != (hh & 1)) bq = (short8){0,0,0,0,0,0,0,0};
                float sc[7][4];
                #pragma unroll
                for (int nt = 0; nt < 7; ++nt) {
                    short8 ak = *(const short8*)(R2 + (nt * 16 + lr) * KSTR + k0 + lk);
                    float4v cc = {msk2[nt][0], msk2[nt][1], msk2[nt][2], msk2[nt][3]};
                    cc = __builtin_amdgcn_mfma_f32_16x16x32_bf16(ak, bq, cc, 0, 0, 0);
                    #pragma unroll
                    for (int r = 0; r < 4; ++r) sc[nt][r] = cc[r];
                }
                // in-register softmax over n (tree max, 2+2 shfl total)
                float mm[7];
                #pragma unroll
                for (int nt = 0; nt < 7; ++nt)
                    mm[nt] = fmaxf(fmaxf(sc[nt][0], sc[nt][1]),
                                   fmaxf(sc[nt][2], sc[nt][3]));
                float m = fmaxf(fmaxf(fmaxf(mm[0], mm[1]), fmaxf(mm[2], mm[3])),
                                fmaxf(fmaxf(mm[4], mm[5]), mm[6]));
                m = fmaxf(m, __shfl_xor(m, 16));
                m = fmaxf(m, __shfl_xor(m, 32));
                float s0 = 0.f, s1 = 0.f, s2 = 0.f, s3 = 0.f;
                #pragma unroll
                for (int nt = 0; nt < 7; ++nt) {
                    float e0 = EXP2(sc[nt][0] - m); sc[nt][0] = e0; s0 += e0;
                    float e1 = EXP2(sc[nt][1] - m); sc[nt][1] = e1; s1 += e1;
                    float e2 = EXP2(sc[nt][2] - m); sc[nt][2] = e2; s2 += e2;
                    float e3 = EXP2(sc[nt][3] - m); sc[nt][3] = e3; s3 += e3;
                }
                float su = (s0 + s1) + (s2 + s3);
                su += __shfl_xor(su, 16);
                su += __shfl_xor(su, 32);
                float inv = RCP(su);                // row inverse (lane-local)
                // P (normalized) -> LDS, packed b64 per nt (rows p = lr)
                #pragma unroll
                for (int nt = 0; nt < 7; ++nt) {
                    uint32_t* d = (uint32_t*)(Pbuf + (pt * 16 + lr) * KSTR
                                              + nt * 16 + (lq << 2));
                    d[0] = pk2(sc[nt][0] * inv, sc[nt][1] * inv);
                    d[1] = pk2(sc[nt][2] * inv, sc[nt][3] * inv);
                }
                float4v o = {0.f, 0.f, 0.f, 0.f};   // PV -> registers
                #pragma unroll
                for (int ks = 0; ks < 128; ks += 32) {
                    short8 a2 = *(const short8*)(Pbuf + (pt * 16 + lr) * KSTR + ks + lk);
                    short8 b2 = *(const short8*)(R3 + (h * 16 + lr) * KSTR + ks + lk);
                    o = __builtin_amdgcn_mfma_f32_16x16x32_bf16(a2, b2, o, 0, 0, 0);
                }
                o4[hh] = o;
            }
        }
        __syncthreads();                            // (4) all P reads done

        // ---- O regs -> R4 (over P/Q) --------------------------------------
        if (wave < 14) {
            #pragma unroll
            for (int hh = 0; hh < 4; ++hh) {
                int h = hg * 4 + hh;
                #pragma unroll
                for (int r = 0; r < 4; ++r)
                    R4[(pt * 16 + (lq << 2) + r) * KSTR + h * 16 + lr] = f2b(o4[hh][r]);
            }
        }
        __syncthreads();                            // (5) O ready

        // ---- Phase E: mh = O@Wc + bc -> hi(R5)+lo(R2) ---------------------
        {
            const int col = 16 * (wave & 7) + lr;
            const int mt0 = (wave >> 3) ? 4 : 0;
            const int mt1 = (wave >> 3) ? 7 : 4;
            short8 bw[4];
            {
                const bf16* rc = WcT + (size_t)col * 128 + lk;
                #pragma unroll
                for (int ss = 0; ss < 4; ++ss) bw[ss] = *(const short8*)(rc + ss * 32);
            }
            float bcv = bc[col];
            for (int mt = mt0; mt < mt1; ++mt) {
                short8 a[4];
                #pragma unroll
                for (int ss = 0; ss < 4; ++ss)
                    a[ss] = *(const short8*)(R4 + (mt * 16 + lr) * KSTR + ss * 32 + lk);
                float4v c = {0.f, 0.f, 0.f, 0.f};
                #pragma unroll
                for (int ss = 0; ss < 4; ++ss)
                    c = __builtin_amdgcn_mfma_f32_16x16x32_bf16(a[ss], bw[ss], c, 0, 0, 0);
                int row0 = mt * 16 + (lq << 2);
                #pragma unroll
                for (int r = 0; r < 4; ++r) {       // two-term bf16 split of mh
                    float m = c[r] + bcv;
                    bf16 hb = f2b(m);
                    R5[(row0 + r) * KSTR + col] = hb;
                    R2[(row0 + r) * KSTR + col] = f2b(m - b2f(hb));
                }
            }
        }
        __syncthreads();                            // (6) mh ready

        // -------- Phase F: swapped score2; constant-max softmax; store -----
        if (wave < 7) {
            const int pt2 = wave;
            short8 bhi[4], blo[4];
            #pragma unroll
            for (int ss = 0; ss < 4; ++ss) {
                bhi[ss] = *(const short8*)(R5 + (pt2 * 16 + lr) * KSTR + ss * 32 + lk);
                blo[ss] = *(const short8*)(R2 + (pt2 * 16 + lr) * KSTR + ss * 32 + lk);
            }
            float sc[7][4];
            #pragma unroll
            for (int nt = 0; nt < 7; ++nt) {
                float4v cc = {0.f, 0.f, 0.f, 0.f};
                #pragma unroll
                for (int ss = 0; ss < 4; ++ss) {
                    short8 ae = *(const short8*)(R1 + (nt * 16 + lr) * KSTR + ss * 32 + lk);
                    cc = __builtin_amdgcn_mfma_f32_16x16x32_bf16(ae, bhi[ss], cc, 0, 0, 0);
                    cc = __builtin_amdgcn_mfma_f32_16x16x32_bf16(ae, blo[ss], cc, 0, 0, 0);
                }
                #pragma unroll
                for (int r = 0; r < 4; ++r) {
                    // tanh via exp2 (const = 1/sqrt(128) * 2 * log2e)
                    float y = EXP2(cc[r] * (0.08838834764831845f * 2.0f * L2E));
                    float t = fmaf(-2.0f, RCP(y + 1.0f), 1.0f);
                    sc[nt][r] = fmaf(10.0f * L2E, t, msk2[nt][r]);
                }
            }
            // softmax with constant max (score2 bounded by +10)
            const float mF = 10.0f * L2E;
            float s0 = 0.f, s1 = 0.f, s2 = 0.f, s3 = 0.f;
            #pragma unroll
            for (int nt = 0; nt < 7; ++nt) {
                float e0 = EXP2(sc[nt][0] - mF); sc[nt][0] = e0; s0 += e0;
                float e1 = EXP2(sc[nt][1] - mF); sc[nt][1] = e1; s1 += e1;
                float e2 = EXP2(sc[nt][2] - mF); sc[nt][2] = e2; s2 += e2;
                float e3 = EXP2(sc[nt][3] - mF); sc[nt][3] = e3; s3 += e3;
            }
            float su = (s0 + s1) + (s2 + s3);
            su += __shfl_xor(su, 16);
            su += __shfl_xor(su, 32);
            float inv = RCP(su);
            const int p = pt2 * 16 + lr;
            if (p < P_) {
                float* orow = outB + (size_t)p * N_;
                #pragma unroll
                for (int nt = 0; nt < 6; ++nt) {
                    F4 ov = { sc[nt][0] * inv, sc[nt][1] * inv,
                              sc[nt][2] * inv, sc[nt][3] * inv };
                    *(F4*)(orow + nt * 16 + (lq << 2)) = ov;
                }
                if (lq == 0) {
                    F4 ov = { sc[6][0] * inv, sc[6][1] * inv,
                              sc[6][2] * inv, sc[6][3] * inv };
                    *(F4*)(orow + 96) = ov;
                } else if (lq == 1) {
                    orow[100] = sc[6][0] * inv;
                }
            }
        }
        if (s + 1 < NPER_) __syncthreads();         // (7) R1/R5/R2 reads done
    }
}

extern "C" void kernel_launch(void* const* d_in, const int* in_sizes, int n_in,
                              void* d_out, int out_size, void* d_ws, size_t ws_size,
                              hipStream_t stream) {
    const float* eln   = (const float*)d_in[0];
    const float* load_ = (const float*)d_in[1];
    const float* time_ = (const float*)d_in[2];
    const float* len_  = (const float*)d_in[3];
    const float* open_ = (const float*)d_in[4];
    const float* mask_ = (const float*)d_in[5];
    const float* enc_  = (const float*)d_in[6];
    const float* Wq    = (const float*)d_in[7];
    const float* Wk    = (const float*)d_in[8];
    const float* Wv    = (const float*)d_in[9];
    const float* Wc    = (const float*)d_in[10];
    const float* bc    = (const float*)d_in[11];
    float* out = (float*)d_out;
    bf16* wsWT = (bf16*)d_ws;                      // 4*16384*2 = 131072 B

    prep_wT<<<dim3(256), dim3(256), 0, stream>>>(Wq, Wk, Wv, Wc, wsWT);
    vrp_kernel<<<dim3(GRID_), dim3(1024), 0, stream>>>(
        eln, load_, time_, len_, open_, mask_, enc_, Wq, bc, wsWT, out);
}

// Round 10
// 356.362 us; speedup vs baseline: 1.1148x; 1.1148x over previous
//
#include <hip/hip_runtime.h>
#include <stdint.h>

#define B_    1024
#define P_    100
#define N_    101
#define EMB_  128
#define H_    8
#define DK_   16
#define GRID_ 256                  // 1 block/CU; each block loops NPER_ samples
#define NPER_ (B_ / GRID_)         // 4

#define ROWS  112          // 7 m-tiles of 16 (covers P=100 / N=101)
#define KSTR  136          // LDS row stride in bf16 elems

typedef uint16_t bf16;
typedef __attribute__((ext_vector_type(8))) short short8;
typedef __attribute__((ext_vector_type(4))) float float4v;

struct F4 { float x, y, z, w; };   // 4-byte-aligned float quad (101-stride safe)

#define L2E 1.4426950408889634f

#if __has_builtin(__builtin_amdgcn_exp2f)
#define EXP2(x) __builtin_amdgcn_exp2f(x)
#else
#define EXP2(x) exp2f(x)
#endif
#if __has_builtin(__builtin_amdgcn_rcpf)
#define RCP(x) __builtin_amdgcn_rcpf(x)
#else
#define RCP(x) (1.0f / (x))
#endif

__device__ __forceinline__ float b2f(bf16 u) {
    union { uint32_t i; float f; } c; c.i = ((uint32_t)u) << 16; return c.f;
}
// round-half-up f32->bf16 (bias then take high 16): 2 ops
__device__ __forceinline__ bf16 f2b(float f) {
    union { float f; uint32_t i; } c; c.f = f;
    return (bf16)((c.i + 0x8000u) >> 16);
}
// packed pair via v_perm byte-select: 3 ops for 2 values
__device__ __forceinline__ uint32_t pk2(float a, float b) {
    union { float f; uint32_t i; } ca, cb; ca.f = a; cb.f = b;
    return __builtin_amdgcn_perm(cb.i + 0x8000u, ca.i + 0x8000u, 0x07060302u);
}

// stage enc/cat f32 rows -> bf16 LDS (short-lived temps: no spill risk)
__device__ __forceinline__ void stage_pair(const float* __restrict__ encN,
                                           const float* __restrict__ elnN,
                                           bf16* __restrict__ encDst,
                                           bf16* __restrict__ catDst,
                                           int i0, int stride)
{
    for (int i = i0; i < ROWS * 32; i += stride) {
        int r = i >> 5, c = (i & 31) << 2;
        uint32_t p0 = 0, p1 = 0;
        if (r < N_) {
            float4 v = *(const float4*)(encN + (size_t)r * EMB_ + c);
            p0 = pk2(v.x, v.y); p1 = pk2(v.z, v.w);
        }
        uint32_t* d = (uint32_t*)(encDst + r * KSTR + c);
        d[0] = p0; d[1] = p1;
        uint32_t q0 = 0, q1 = 0;
        if (r < P_) {
            float4 v = *(const float4*)(elnN + (size_t)r * EMB_ + c);
            q0 = pk2(v.x, v.y); q1 = pk2(v.z, v.w);
        }
        uint32_t* d2 = (uint32_t*)(catDst + r * KSTR + c);
        d2[0] = q0; d2[1] = q1;
    }
}

__device__ __forceinline__ void stage_s4(const float* __restrict__ l,
                                         const float* __restrict__ t,
                                         const float* __restrict__ n,
                                         const float* __restrict__ o,
                                         int b, float* __restrict__ sS4,
                                         int i0, int stride)
{
    for (int i = i0; i < ROWS * 4; i += stride) {
        int r = i >> 2, j = i & 3;
        float v = 0.f;
        if (r < P_) {
            const float* s4p = (j == 0) ? l : (j == 1) ? t : (j == 2) ? n : o;
            v = s4p[(size_t)b * P_ + r];
        }
        sS4[i] = v;
    }
}

// ---- prep: W f32 [k][o] -> ws bf16 W^T [o][k], order: Wk, Wv, Wq, Wc ------
__global__ __launch_bounds__(256)
void prep_wT(const float* __restrict__ Wq, const float* __restrict__ Wk,
             const float* __restrict__ Wv, const float* __restrict__ Wc,
             bf16* __restrict__ ws) {
    int idx = blockIdx.x * 256 + threadIdx.x;      // 65536 threads
    int w = idx >> 14, rem = idx & 16383;
    int k = rem >> 7, o = rem & 127;               // o innermost: coalesced read
    const float* W = (w == 0) ? Wk : (w == 1) ? Wv : (w == 2) ? Wq : Wc;
    ws[((size_t)w << 14) + o * 128 + k] = f2b(W[(size_t)k * 128 + o]);
}

__global__ __launch_bounds__(1024, 4)
void vrp_kernel(const float* __restrict__ eln,
                const float* __restrict__ load_,
                const float* __restrict__ time_,
                const float* __restrict__ len_,
                const float* __restrict__ open_,
                const float* __restrict__ mask_,
                const float* __restrict__ enc_,
                const float* __restrict__ Wq,
                const float* __restrict__ bc,
                const bf16* __restrict__ wsWT,
                float* __restrict__ out)
{
    const int tid  = threadIdx.x;
    const int wave = tid >> 6;
    const int lane = tid & 63;
    const int lr = lane & 15, lq = lane >> 4, lk = lq << 3;

    // Buffers: A1/A3 = 128-row, parity-alternating enc / V^T.
    //   R2 = K / mh-lo ; R4 = cat / P(hg=1) / O ; R5 = Q' / P(hg=0) / mh-hi
    // Per sample s: encBuf = (s odd ? A3 : A1), vBuf = the other.
    // During F(s): vBuf, R4, sS4 are dead -> waves 7-15 stage sample s+1.
    __shared__ bf16 smem[80512];                   // 161024 B
    __shared__ float sS4[ROWS * 4];                // 1792 B  (total 162816)
    bf16* const A1 = smem;
    bf16* const R2 = smem + 17408;
    bf16* const A3 = smem + 32640;
    bf16* const R4 = smem + 50048;
    bf16* const R5 = smem + 65280;

    const bf16* WkT = wsWT;
    const bf16* WvT = wsWT + 16384;
    const bf16* WqT = wsWT + 32768;
    const bf16* WcT = wsWT + 49152;

    // ---- prologue: V^T-pad safety zeroes + stage sample 0 -----------------
    // A3 all 128 rows pad cols 112..127 (A3 is V^T for s=0; rows 0..111 pads
    // of both bufs get finite enc values from staging thereafter).
    // A1 rows 112..127 pads (never touched by enc staging).
    if (tid < 1152) {
        bf16* base; int r;
        if (tid < 1024) { base = A3; r = tid >> 3; }
        else            { base = A1; r = 112 + ((tid - 1024) >> 3); }
        ((uint32_t*)(base + r * KSTR + 112))[tid & 7] = 0;
    }
    {
        const int b0 = blockIdx.x * NPER_;
        stage_pair(enc_ + (size_t)b0 * N_ * EMB_, eln + (size_t)b0 * P_ * EMB_,
                   A1, R4, tid, 1024);
        stage_s4(load_, time_, len_, open_, b0, sS4, tid, 1024);
    }
    __syncthreads();                               // (1) sample 0 staged

    for (int s = 0; s < NPER_; ++s) {
        const int b = blockIdx.x * NPER_ + s;
        const float* maskB = mask_ + (size_t)b * P_ * N_;
        float*       outB  = out   + (size_t)b * P_ * N_;
        bf16* const encBuf = (s & 1) ? A3 : A1;
        bf16* const vBuf   = (s & 1) ? A1 : A3;

        // mask gather issued first: HBM latency hides under all of B/C.
        const int hg = (wave >= 7) ? 1 : 0;
        const int pt = wave - hg * 7;
        float msk2[7][4];                          // reused by F (waves 0-6)
        if (wave < 14) {
            const int p = pt * 16 + lr;
            const bool pvalid = (p < P_);
            const float* mrow = maskB + (size_t)(pvalid ? p : 0) * N_;
            #pragma unroll
            for (int nt = 0; nt < 6; ++nt) {       // n <= 95 < 101: packed
                int nb = nt * 16 + (lq << 2);
                F4 mv = *(const F4*)(mrow + nb);
                msk2[nt][0] = pvalid ? mv.x * L2E : 0.f;
                msk2[nt][1] = pvalid ? mv.y * L2E : 0.f;
                msk2[nt][2] = pvalid ? mv.z * L2E : 0.f;
                msk2[nt][3] = pvalid ? mv.w * L2E : 0.f;
            }
            if (lq == 0) {                         // nt=6 tail: n=96+4lq+r
                F4 mv = *(const F4*)(mrow + 96);
                msk2[6][0] = pvalid ? mv.x * L2E : 0.f;
                msk2[6][1] = pvalid ? mv.y * L2E : 0.f;
                msk2[6][2] = pvalid ? mv.z * L2E : 0.f;
                msk2[6][3] = pvalid ? mv.w * L2E : 0.f;
            } else if (lq == 1) {
                msk2[6][0] = pvalid ? mrow[100] * L2E : 0.f;
                msk2[6][1] = -3.0e38f; msk2[6][2] = -3.0e38f; msk2[6][3] = -3.0e38f;
            } else {
                msk2[6][0] = -3.0e38f; msk2[6][1] = -3.0e38f;
                msk2[6][2] = -3.0e38f; msk2[6][3] = -3.0e38f;
            }
        }

        // ------- Phase B+C: K->R2, V^T->vBuf, Q'->R5 ----------------------
        {
            const int col = 16 * (wave & 7) + lr;
            const int mt0 = (wave >> 3) ? 4 : 0;
            const int mt1 = (wave >> 3) ? 7 : 4;
            short8 bk[4], bv[4], bq[4];
            {
                const bf16* rk = WkT + (size_t)col * 128 + lk;
                const bf16* rv = WvT + (size_t)col * 128 + lk;
                const bf16* rq = WqT + (size_t)col * 128 + lk;
                #pragma unroll
                for (int ss = 0; ss < 4; ++ss) {
                    bk[ss] = *(const short8*)(rk + ss * 32);
                    bv[ss] = *(const short8*)(rv + ss * 32);
                    bq[ss] = *(const short8*)(rq + ss * 32);
                }
            }
            // 4 extra Wq rows straight from global (L2-hot; sWq4 dropped)
            float w0 = Wq[(size_t)(EMB_ + 0) * EMB_ + col];
            float w1 = Wq[(size_t)(EMB_ + 1) * EMB_ + col];
            float w2 = Wq[(size_t)(EMB_ + 2) * EMB_ + col];
            float w3 = Wq[(size_t)(EMB_ + 3) * EMB_ + col];
            for (int mt = mt0; mt < mt1; ++mt) {
                short8 a[4];
                #pragma unroll
                for (int ss = 0; ss < 4; ++ss)
                    a[ss] = *(const short8*)(encBuf + (mt * 16 + lr) * KSTR + ss * 32 + lk);
                float4v ck = {0.f, 0.f, 0.f, 0.f}, cv = {0.f, 0.f, 0.f, 0.f};
                #pragma unroll
                for (int ss = 0; ss < 4; ++ss) {
                    ck = __builtin_amdgcn_mfma_f32_16x16x32_bf16(a[ss], bk[ss], ck, 0, 0, 0);
                    cv = __builtin_amdgcn_mfma_f32_16x16x32_bf16(a[ss], bv[ss], cv, 0, 0, 0);
                }
                int n0 = mt * 16 + (lq << 2);
                #pragma unroll
                for (int r = 0; r < 4; ++r)
                    R2[(n0 + r) * KSTR + col] = f2b(ck[r]);       // K [n][col]
                uint32_t* d = (uint32_t*)(vBuf + col * KSTR + n0); // V^T [d][n]
                d[0] = pk2(cv[0], cv[1]);
                d[1] = pk2(cv[2], cv[3]);
                // Q' = 0.25*log2e*(cat@Wq)  (log2e baked for exp2)
                short8 aq[4];
                #pragma unroll
                for (int ss = 0; ss < 4; ++ss)
                    aq[ss] = *(const short8*)(R4 + (mt * 16 + lr) * KSTR + ss * 32 + lk);
                float4v cq = {0.f, 0.f, 0.f, 0.f};
                #pragma unroll
                for (int ss = 0; ss < 4; ++ss)
                    cq = __builtin_amdgcn_mfma_f32_16x16x32_bf16(aq[ss], bq[ss], cq, 0, 0, 0);
                int row0 = mt * 16 + (lq << 2);
                #pragma unroll
                for (int r = 0; r < 4; ++r) {
                    const float* s4 = sS4 + (row0 + r) * 4;
                    float acc = cq[r] + s4[0] * w0 + s4[1] * w1 + s4[2] * w2 + s4[3] * w3;
                    R5[(row0 + r) * KSTR + col] = f2b(acc * (0.25f * L2E));
                }
            }
        }
        __syncthreads();                           // (2) K/V/Q ready

        short8 q0, q1;                             // Q hoist (R5)
        if (wave < 14) {
            q0 = *(const short8*)(R5 + (pt * 16 + lr) * KSTR + hg * 64 + lk);
            q1 = *(const short8*)(R5 + (pt * 16 + lr) * KSTR + hg * 64 + 32 + lk);
        }
        __syncthreads();                           // (3) Q consumed -> P bufs

        // -------- Phase D: swapped QK^T, P->LDS roundtrip PV ---------------
        float4v o4[4];
        if (wave < 14) {
            bf16* Pbuf = hg ? R4 : R5;
            {   // zero pad cols 112..127 of my p-tile rows
                uint32_t* z = (uint32_t*)(Pbuf + (pt * 16 + lr) * KSTR + 112 + (lq << 2));
                z[0] = 0; z[1] = 0;
            }
            #pragma unroll
            for (int hh = 0; hh < 4; ++hh) {
                int h  = hg * 4 + hh;
                int k0 = hg * 64 + (hh >> 1) * 32; // head's 32-wide k-window
                short8 bq = (hh < 2) ? q0 : q1;
                if ((lq >> 1) != (hh & 1)) bq = (short8){0,0,0,0,0,0,0,0};
                float sc[7][4];
                #pragma unroll
                for (int nt = 0; nt < 7; ++nt) {
                    short8 ak = *(const short8*)(R2 + (nt * 16 + lr) * KSTR + k0 + lk);
                    float4v cc = {msk2[nt][0], msk2[nt][1], msk2[nt][2], msk2[nt][3]};
                    cc = __builtin_amdgcn_mfma_f32_16x16x32_bf16(ak, bq, cc, 0, 0, 0);
                    #pragma unroll
                    for (int r = 0; r < 4; ++r) sc[nt][r] = cc[r];
                }
                // in-register softmax over n (tree max, 2+2 shfl total)
                float mm[7];
                #pragma unroll
                for (int nt = 0; nt < 7; ++nt)
                    mm[nt] = fmaxf(fmaxf(sc[nt][0], sc[nt][1]),
                                   fmaxf(sc[nt][2], sc[nt][3]));
                float m = fmaxf(fmaxf(fmaxf(mm[0], mm[1]), fmaxf(mm[2], mm[3])),
                                fmaxf(fmaxf(mm[4], mm[5]), mm[6]));
                m = fmaxf(m, __shfl_xor(m, 16));
                m = fmaxf(m, __shfl_xor(m, 32));
                float s0 = 0.f, s1 = 0.f, s2 = 0.f, s3 = 0.f;
                #pragma unroll
                for (int nt = 0; nt < 7; ++nt) {
                    float e0 = EXP2(sc[nt][0] - m); sc[nt][0] = e0; s0 += e0;
                    float e1 = EXP2(sc[nt][1] - m); sc[nt][1] = e1; s1 += e1;
                    float e2 = EXP2(sc[nt][2] - m); sc[nt][2] = e2; s2 += e2;
                    float e3 = EXP2(sc[nt][3] - m); sc[nt][3] = e3; s3 += e3;
                }
                float su = (s0 + s1) + (s2 + s3);
                su += __shfl_xor(su, 16);
                su += __shfl_xor(su, 32);
                float inv = RCP(su);               // row inverse (lane-local)
                #pragma unroll
                for (int nt = 0; nt < 7; ++nt) {   // P -> LDS, packed b64
                    uint32_t* d = (uint32_t*)(Pbuf + (pt * 16 + lr) * KSTR
                                              + nt * 16 + (lq << 2));
                    d[0] = pk2(sc[nt][0] * inv, sc[nt][1] * inv);
                    d[1] = pk2(sc[nt][2] * inv, sc[nt][3] * inv);
                }
                float4v o = {0.f, 0.f, 0.f, 0.f};  // PV -> registers
                #pragma unroll
                for (int ks = 0; ks < 128; ks += 32) {
                    short8 a2 = *(const short8*)(Pbuf + (pt * 16 + lr) * KSTR + ks + lk);
                    short8 b2 = *(const short8*)(vBuf + (h * 16 + lr) * KSTR + ks + lk);
                    o = __builtin_amdgcn_mfma_f32_16x16x32_bf16(a2, b2, o, 0, 0, 0);
                }
                o4[hh] = o;
            }
        }
        __syncthreads();                           // (4) all P/V reads done

        // ---- O regs -> R4 (over P1/cat) -----------------------------------
        if (wave < 14) {
            #pragma unroll
            for (int hh = 0; hh < 4; ++hh) {
                int h = hg * 4 + hh;
                #pragma unroll
                for (int r = 0; r < 4; ++r)
                    R4[(pt * 16 + (lq << 2) + r) * KSTR + h * 16 + lr] = f2b(o4[hh][r]);
            }
        }
        __syncthreads();                           // (5) O ready

        // ---- Phase E: mh = O@Wc + bc -> hi(R5)+lo(R2) ---------------------
        {
            const int col = 16 * (wave & 7) + lr;
            const int mt0 = (wave >> 3) ? 4 : 0;
            const int mt1 = (wave >> 3) ? 7 : 4;
            short8 bw[4];
            {
                const bf16* rc = WcT + (size_t)col * 128 + lk;
                #pragma unroll
                for (int ss = 0; ss < 4; ++ss) bw[ss] = *(const short8*)(rc + ss * 32);
            }
            float bcv = bc[col];
            for (int mt = mt0; mt < mt1; ++mt) {
                short8 a[4];
                #pragma unroll
                for (int ss = 0; ss < 4; ++ss)
                    a[ss] = *(const short8*)(R4 + (mt * 16 + lr) * KSTR + ss * 32 + lk);
                float4v c = {0.f, 0.f, 0.f, 0.f};
                #pragma unroll
                for (int ss = 0; ss < 4; ++ss)
                    c = __builtin_amdgcn_mfma_f32_16x16x32_bf16(a[ss], bw[ss], c, 0, 0, 0);
                int row0 = mt * 16 + (lq << 2);
                #pragma unroll
                for (int r = 0; r < 4; ++r) {      // two-term bf16 split of mh
                    float m = c[r] + bcv;
                    bf16 hb = f2b(m);
                    R5[(row0 + r) * KSTR + col] = hb;
                    R2[(row0 + r) * KSTR + col] = f2b(m - b2f(hb));
                }
            }
        }
        __syncthreads();                           // (6) mh ready; R4/vBuf dead

        // -------- Phase F (waves 0-6) ∥ next-sample staging (waves 7-15) ---
        if (wave < 7) {
            const int pt2 = wave;
            short8 bhi[4], blo[4];
            #pragma unroll
            for (int ss = 0; ss < 4; ++ss) {
                bhi[ss] = *(const short8*)(R5 + (pt2 * 16 + lr) * KSTR + ss * 32 + lk);
                blo[ss] = *(const short8*)(R2 + (pt2 * 16 + lr) * KSTR + ss * 32 + lk);
            }
            float sc[7][4];
            #pragma unroll
            for (int nt = 0; nt < 7; ++nt) {
                float4v cc = {0.f, 0.f, 0.f, 0.f};
                #pragma unroll
                for (int ss = 0; ss < 4; ++ss) {
                    short8 ae = *(const short8*)(encBuf + (nt * 16 + lr) * KSTR + ss * 32 + lk);
                    cc = __builtin_amdgcn_mfma_f32_16x16x32_bf16(ae, bhi[ss], cc, 0, 0, 0);
                    cc = __builtin_amdgcn_mfma_f32_16x16x32_bf16(ae, blo[ss], cc, 0, 0, 0);
                }
                #pragma unroll
                for (int r = 0; r < 4; ++r) {
                    // tanh via exp2 (const = 1/sqrt(128) * 2 * log2e)
                    float y = EXP2(cc[r] * (0.08838834764831845f * 2.0f * L2E));
                    float t = fmaf(-2.0f, RCP(y + 1.0f), 1.0f);
                    sc[nt][r] = fmaf(10.0f * L2E, t, msk2[nt][r]);
                }
            }
            // softmax with constant max (score2 bounded by +10)
            const float mF = 10.0f * L2E;
            float s0 = 0.f, s1 = 0.f, s2 = 0.f, s3 = 0.f;
            #pragma unroll
            for (int nt = 0; nt < 7; ++nt) {
                float e0 = EXP2(sc[nt][0] - mF); sc[nt][0] = e0; s0 += e0;
                float e1 = EXP2(sc[nt][1] - mF); sc[nt][1] = e1; s1 += e1;
                float e2 = EXP2(sc[nt][2] - mF); sc[nt][2] = e2; s2 += e2;
                float e3 = EXP2(sc[nt][3] - mF); sc[nt][3] = e3; s3 += e3;
            }
            float su = (s0 + s1) + (s2 + s3);
            su += __shfl_xor(su, 16);
            su += __shfl_xor(su, 32);
            float inv = RCP(su);
            const int p = pt2 * 16 + lr;
            if (p < P_) {
                float* orow = outB + (size_t)p * N_;
                #pragma unroll
                for (int nt = 0; nt < 6; ++nt) {
                    F4 ov = { sc[nt][0] * inv, sc[nt][1] * inv,
                              sc[nt][2] * inv, sc[nt][3] * inv };
                    *(F4*)(orow + nt * 16 + (lq << 2)) = ov;
                }
                if (lq == 0) {
                    F4 ov = { sc[6][0] * inv, sc[6][1] * inv,
                              sc[6][2] * inv, sc[6][3] * inv };
                    *(F4*)(orow + 96) = ov;
                } else if (lq == 1) {
                    orow[100] = sc[6][0] * inv;
                }
            }
        } else if (s + 1 < NPER_) {
            // waves 7-15 (576 threads): stage sample s+1 while F computes.
            // enc(s+1) -> vBuf (dead after PV), cat(s+1) -> R4 (dead after E),
            // s4 -> sS4 (dead after B/C). Temps are loop-local: no spill.
            const int bn = b + 1;
            stage_pair(enc_ + (size_t)bn * N_ * EMB_, eln + (size_t)bn * P_ * EMB_,
                       vBuf, R4, tid - 448, 576);
            stage_s4(load_, time_, len_, open_, bn, sS4, tid - 448, 576);
        }
        if (s + 1 < NPER_) __syncthreads();        // (7) F reads + staging done
    }
}

extern "C" void kernel_launch(void* const* d_in, const int* in_sizes, int n_in,
                              void* d_out, int out_size, void* d_ws, size_t ws_size,
                              hipStream_t stream) {
    const float* eln   = (const float*)d_in[0];
    const float* load_ = (const float*)d_in[1];
    const float* time_ = (const float*)d_in[2];
    const float* len_  = (const float*)d_in[3];
    const float* open_ = (const float*)d_in[4];
    const float* mask_ = (const float*)d_in[5];
    const float* enc_  = (const float*)d_in[6];
    const float* Wq    = (const float*)d_in[7];
    const float* Wk    = (const float*)d_in[8];
    const float* Wv    = (const float*)d_in[9];
    const float* Wc    = (const float*)d_in[10];
    const float* bc    = (const float*)d_in[11];
    float* out = (float*)d_out;
    bf16* wsWT = (bf16*)d_ws;                      // 4*16384*2 = 131072 B

    prep_wT<<<dim3(256), dim3(256), 0, stream>>>(Wq, Wk, Wv, Wc, wsWT);
    vrp_kernel<<<dim3(GRID_), dim3(1024), 0, stream>>>(
        eln, load_, time_, len_, open_, mask_, enc_, Wq, bc, wsWT, out);
}